// Round 14
// baseline (286.307 us; speedup 1.0000x reference)
//
#include <hip/hip_runtime.h>
#include <type_traits>

// ---------------------------------------------------------------------------
// GPT block forward: B=2, S=2048, D=1024, H=16, DH=64
// Round 14: GEMM K-loop VALU cut — hoisted LDS read/stage pointers (compile-
// time buffer offsets folded into ds_read offset immediates), K-loop unrolled
// x2 over buffers. Sync schedule identical to round 13 (counted vmcnt + raw
// barriers). Attention (kv-split x4)/merge/LN unchanged from round 12/13.
// ---------------------------------------------------------------------------

typedef unsigned short u16;
typedef short s16x8 __attribute__((ext_vector_type(8)));
typedef unsigned short u16x4 __attribute__((ext_vector_type(4)));
typedef float f32x4 __attribute__((ext_vector_type(4)));
typedef float f32x16 __attribute__((ext_vector_type(16)));

__device__ __forceinline__ u16 f2b(float f) {
    union { float f; unsigned u; } x{f};
    unsigned r = x.u + 0x7FFFu + ((x.u >> 16) & 1u);  // RNE
    return (u16)(r >> 16);
}

__device__ __forceinline__ float b2f(u16 v) {
    union { unsigned u; float f; } x;
    x.u = ((unsigned)v) << 16;
    return x.f;
}

__device__ __forceinline__ f32x4 mfma16(s16x8 a, s16x8 b, f32x4 c) {
    return __builtin_amdgcn_mfma_f32_16x16x32_bf16(a, b, c, 0, 0, 0);
}

__device__ __forceinline__ f32x16 mfma32(s16x8 a, s16x8 b, f32x16 c) {
    return __builtin_amdgcn_mfma_f32_32x32x16_bf16(a, b, c, 0, 0, 0);
}

__device__ __forceinline__ int cvtpk(float a, float b) {
    int r;
    asm("v_cvt_pk_bf16_f32 %0, %1, %2" : "=v"(r) : "v"(a), "v"(b));
    return r;
}

__device__ __forceinline__ void gld_lds16(const u16* g, const u16* l) {
    __builtin_amdgcn_global_load_lds(
        (const __attribute__((address_space(1))) void*)g,
        (__attribute__((address_space(3))) void*)l, 16, 0, 0);
}

__device__ __forceinline__ void hard_barrier() {
    __builtin_amdgcn_sched_barrier(0);
    __builtin_amdgcn_s_barrier();
    __builtin_amdgcn_sched_barrier(0);
}

// --------------------------- fp32 -> bf16 convert ---------------------------
__global__ __launch_bounds__(256) void cvt_bf16(const float* __restrict__ in,
                                                u16* __restrict__ out, int n4) {
    int i = blockIdx.x * 256 + threadIdx.x;
    if (i < n4) {
        float4 v = ((const float4*)in)[i];
        u16x4 o = {f2b(v.x), f2b(v.y), f2b(v.z), f2b(v.w)};
        ((u16x4*)out)[i] = o;
    }
}

// ------------------- transpose fp32 [K,N] -> bf16 [N,K] ---------------------
__global__ __launch_bounds__(256) void transpose_bf16(const float* __restrict__ W,
                                                      u16* __restrict__ WT,
                                                      int K, int N) {
    __shared__ float t[32][33];
    int tx = threadIdx.x & 31, ty = threadIdx.x >> 5;
    int n0 = blockIdx.x * 32, k0 = blockIdx.y * 32;
    #pragma unroll
    for (int r = ty; r < 32; r += 8)
        t[r][tx] = W[(size_t)(k0 + r) * N + n0 + tx];
    __syncthreads();
    #pragma unroll
    for (int r = ty; r < 32; r += 8)
        WT[(size_t)(n0 + r) * K + k0 + tx] = f2b(t[tx][r]);
}

// ------------- MFMA GEMM, counted-vmcnt pipeline, hoisted addrs -------------
// BM=128, BK=64, 4 waves (2x2), wave tile 64 x BN/2. Full row&7 granule-XOR
// swizzle (0 conflicts, r10/r11). Schedule (r13 verified): wait vmcnt(L) =
// next tile's loads stay in flight; raw barriers; stage tile k+2 after the
// post-compute barrier. NEW: all LDS read/stage pointers hoisted, buffer
// selection via compile-time offsets (ds_read offset immediates).
template<int BN, bool GELU, typename OT>
__global__ __launch_bounds__(256) void gemm_pl(const u16* __restrict__ A,
                                               const u16* __restrict__ BT,
                                               const float* __restrict__ bias,
                                               OT* __restrict__ C,
                                               int M, int N, int K, int ldc) {
    constexpr int NF = BN / 32;
    constexpr int BNI = BN / 32;          // B loads per thread per tile
    constexpr int LTOT = 4 + BNI;         // loads per thread per tile
    __shared__ u16 As[2][128 * 64];
    __shared__ u16 Bs[2][BN * 64];

    int t = threadIdx.x;
    int w = t >> 6, l = t & 63, l16 = l & 15, lh = l >> 4;
    int wr = w >> 1, wc = w & 1;

    int nbm = M >> 7;
    int cpx = gridDim.x >> 3;
    int id = blockIdx.x;
    int id2 = (id & 7) * cpx + (id >> 3);
    size_t m0 = (size_t)(id2 % nbm) * 128;
    size_t n0 = (size_t)(id2 / nbm) * BN;

    int rowA = t >> 3;
    int gc2 = (t & 7) ^ (rowA & 7);
    const u16* Ag = A + (m0 + rowA) * (size_t)K + gc2 * 8;
    const u16* Bg = BT + (n0 + rowA) * (size_t)K + gc2 * 8;
    int wbase = w * 512;

    f32x4 acc[4][NF] = {};
    int rx = (l16 & 7) * 8;

    // hoisted LDS read pointers (buf0 base; buf1 = +const, folds into offset:)
    const s16x8* pa[2][4];
    const s16x8* pb[2][NF];
    #pragma unroll
    for (int ks = 0; ks < 2; ++ks) {
        #pragma unroll
        for (int fm = 0; fm < 4; ++fm) {
            int row = wr * 64 + fm * 16 + l16;
            int col = ((ks * 4 + lh) * 8) ^ rx;
            pa[ks][fm] = (const s16x8*)&As[0][row * 64 + col];
        }
        #pragma unroll
        for (int fn = 0; fn < NF; ++fn) {
            int row = wc * (BN / 2) + fn * 16 + l16;
            int col = ((ks * 4 + lh) * 8) ^ rx;
            pb[ks][fn] = (const s16x8*)&Bs[0][row * 64 + col];
        }
    }
    // hoisted staging dest pointers (buf0 base)
    const u16* dA[4];
    const u16* dB[BNI];
    #pragma unroll
    for (int j = 0; j < 4; ++j) dA[j] = &As[0][j * 2048 + wbase];
    #pragma unroll
    for (int j = 0; j < BNI; ++j) dB[j] = &Bs[0][j * 2048 + wbase];

    // prologue: tile 0 -> buf0, tile 1 -> buf1
    #pragma unroll
    for (int j = 0; j < 4; ++j) gld_lds16(Ag + (size_t)j * 32 * K, dA[j]);
    #pragma unroll
    for (int j = 0; j < BNI; ++j) gld_lds16(Bg + (size_t)j * 32 * K, dB[j]);
    #pragma unroll
    for (int j = 0; j < 4; ++j)
        gld_lds16(Ag + 64 + (size_t)j * 32 * K, dA[j] + 8192);
    #pragma unroll
    for (int j = 0; j < BNI; ++j)
        gld_lds16(Bg + 64 + (size_t)j * 32 * K, dB[j] + BN * 64);

#define GTILE(CB, kk, LAST)                                                   \
    {                                                                         \
        if (LAST) asm volatile("s_waitcnt vmcnt(0)" ::: "memory");            \
        else      asm volatile("s_waitcnt vmcnt(%0)" :: "n"(LTOT) : "memory");\
        hard_barrier();                                                       \
        __builtin_amdgcn_s_setprio(1);                                        \
        _Pragma("unroll")                                                     \
        for (int ks = 0; ks < 2; ++ks) {                                      \
            s16x8 af[4], bf[NF];                                              \
            _Pragma("unroll")                                                 \
            for (int fm = 0; fm < 4; ++fm) af[fm] = pa[ks][fm][(CB) * 1024];  \
            _Pragma("unroll")                                                 \
            for (int fn = 0; fn < NF; ++fn) bf[fn] = pb[ks][fn][(CB) * BN * 8];\
            _Pragma("unroll")                                                 \
            for (int fm = 0; fm < 4; ++fm)                                    \
                _Pragma("unroll")                                             \
                for (int fn = 0; fn < NF; ++fn)                               \
                    acc[fm][fn] = mfma16(af[fm], bf[fn], acc[fm][fn]);        \
        }                                                                     \
        __builtin_amdgcn_s_setprio(0);                                        \
        hard_barrier();                                                       \
        if ((kk) + 128 < K) {                                                 \
            const u16* Ap = Ag + (kk) + 128;                                  \
            _Pragma("unroll")                                                 \
            for (int j = 0; j < 4; ++j)                                       \
                gld_lds16(Ap + (size_t)j * 32 * K, dA[j] + (CB) * 8192);      \
            const u16* Bp = Bg + (kk) + 128;                                  \
            _Pragma("unroll")                                                 \
            for (int j = 0; j < BNI; ++j)                                     \
                gld_lds16(Bp + (size_t)j * 32 * K, dB[j] + (CB) * (BN * 64)); \
        }                                                                     \
    }

    // K is a multiple of 128 here (1024 or 4096)
    for (int k0 = 0; k0 < K; k0 += 128) {
        GTILE(0, k0, (k0 + 64 >= K))
        GTILE(1, k0 + 64, (k0 + 128 >= K))
    }
#undef GTILE

    #pragma unroll
    for (int fn = 0; fn < NF; ++fn) {
        size_t col = n0 + wc * (BN / 2) + fn * 16 + l16;
        float bs = bias[col];
        #pragma unroll
        for (int fm = 0; fm < 4; ++fm) {
            size_t row0 = m0 + wr * 64 + fm * 16 + lh * 4;
            #pragma unroll
            for (int i = 0; i < 4; ++i) {
                float v = acc[fm][fn][i] + bs;
                if constexpr (GELU) {
                    float x3 = v * v * v;
                    v = 0.5f * v * (1.f + tanhf(0.7978845608f * (v + 0.044715f * x3)));
                }
                if constexpr (std::is_same<OT, u16>::value)
                    C[(row0 + i) * ldc + col] = f2b(v);
                else
                    C[(row0 + i) * ldc + col] = v;
            }
        }
    }
}

// --------------------------- causal attention -------------------------------
// kv-split x4 (round 12, verified): block = (quarter, pair pr, bh).
__global__ __launch_bounds__(256) void attn_kernel(const u16* __restrict__ qkv,
                                                   u16* __restrict__ p0,
                                                   u16* __restrict__ p1,
                                                   u16* __restrict__ p2,
                                                   u16* __restrict__ p3,
                                                   float2* __restrict__ stats) {
    constexpr int S = 2048, D3 = 3072, Dm = 1024;
    __shared__ u16 Kl[2][64 * 64];
    __shared__ u16 Vt[2][64 * 64];

    int t = threadIdx.x;
    int w = t >> 6, l = t & 63;
    int l32 = l & 31, hi = l >> 5;
    int bid = blockIdx.x;
    int bh = bid & 31;
    int pr = (bid >> 5) & 7;
    int quar = bid >> 8;                // 0..3
    int b = bh >> 4, h = bh & 15;
    size_t base = (size_t)b * S * D3;

    u16* pout = quar == 0 ? p0 : (quar == 1 ? p1 : (quar == 2 ? p2 : p3));

    int rK0 = t >> 3, gK = t & 7;
    int rK1 = rK0 + 32;
    size_t koff0 = (size_t)rK0 * D3 + (size_t)((gK ^ (rK0 & 7)) * 8);
    size_t koff1 = (size_t)rK1 * D3 + (size_t)((gK ^ (rK1 & 7)) * 8);
    const u16* kbase = qkv + base + Dm + h * 64;
    const u16* vbase = qkv + base + 2 * Dm + h * 64 + w * 16;

    constexpr float cexp = 0.18033688011112042f;   // 0.125 * log2(e)
    constexpr float THR = 64.0f;                    // defer-max threshold
    int xg = l32 & 7;

    #pragma unroll 1
    for (int ph = 0; ph < 2; ++ph) {
        int qt = ph ? (15 - pr) : pr;
        int qb = qt * 128 + w * 32;
        int nst = 2 * (qt + 1);
        int c0 = (nst * quar) >> 2;
        int c1 = (nst * (quar + 1)) >> 2;

        f32x16 O0 = {}, O1 = {};
        float m = -1e30f, lr = 0.f;

        if (c0 < c1) {
            s16x8 qf[4];
            const u16* qp = qkv + base + (size_t)(qb + l32) * D3 + h * 64 + hi * 8;
            #pragma unroll
            for (int kk = 0; kk < 4; ++kk)
                qf[kk] = *(const s16x8*)(qp + kk * 16);

            size_t kc0 = (size_t)c0 * 64 * D3;
            gld_lds16(kbase + kc0 + koff0, &Kl[0][w * 512]);
            gld_lds16(kbase + kc0 + koff1, &Kl[0][2048 + w * 512]);
            {
                const u16* vp = vbase + (size_t)(c0 * 64 + l) * D3;
                s16x8 pv0 = *(const s16x8*)vp;
                s16x8 pv1 = *(const s16x8*)(vp + 8);
                #pragma unroll
                for (int e = 0; e < 8; ++e) {
                    int d0 = w * 16 + e, d1 = w * 16 + 8 + e;
                    Vt[0][d0 * 64 + (l ^ ((d0 & 7) << 3))] = (u16)pv0[e];
                    Vt[0][d1 * 64 + (l ^ ((d1 & 7) << 3))] = (u16)pv1[e];
                }
            }
            __syncthreads();

            #pragma unroll 1
            for (int sc = c0; sc < c1; ++sc) {
                int cur = (sc - c0) & 1;
                bool pre = (sc + 1 < c1);
                s16x8 v0, v1;
                if (pre) {
                    size_t koffc = (size_t)(sc + 1) * 64 * D3;
                    gld_lds16(kbase + koffc + koff0, &Kl[cur ^ 1][w * 512]);
                    gld_lds16(kbase + koffc + koff1, &Kl[cur ^ 1][2048 + w * 512]);
                    const u16* vp = vbase + (size_t)((sc + 1) * 64 + l) * D3;
                    v0 = *(const s16x8*)vp;
                    v1 = *(const s16x8*)(vp + 8);
                }

                int kvb = sc * 64;
                int navail = ((qb - kvb) >> 5) + 1;
                if (navail > 0) {
                    if (navail > 2) navail = 2;
                    const u16* Kc = Kl[cur];
                    const u16* Vc = Vt[cur];
                    f32x16 sa0 = {}, sa1 = {};
                    #pragma unroll
                    for (int kk = 0; kk < 4; ++kk) {
                        s16x8 kf = *(const s16x8*)&Kc[l32 * 64 + (((2 * kk + hi) ^ xg) * 8)];
                        sa0 = mfma32(kf, qf[kk], sa0);
                    }
                    if (navail == 2) {
                        #pragma unroll
                        for (int kk = 0; kk < 4; ++kk) {
                            s16x8 kf = *(const s16x8*)&Kc[(32 + l32) * 64 + (((2 * kk + hi) ^ xg) * 8)];
                            sa1 = mfma32(kf, qf[kk], sa1);
                        }
                    }
                    bool diag0 = (kvb == qb);
                    bool diag1 = (kvb + 32 == qb);
                    float p[32];
                    float mx = -1e30f;
                    #pragma unroll
                    for (int reg = 0; reg < 16; ++reg) {
                        int kvloc = (reg & 3) + 8 * (reg >> 2) + 4 * hi;
                        float s0 = sa0[reg];
                        if (diag0 && kvloc > l32) s0 = -1e30f;
                        p[reg] = s0;
                        mx = fmaxf(mx, s0);
                    }
                    if (navail == 2) {
                        #pragma unroll
                        for (int reg = 0; reg < 16; ++reg) {
                            int kvloc = (reg & 3) + 8 * (reg >> 2) + 4 * hi;
                            float s1 = sa1[reg];
                            if (diag1 && kvloc > l32) s1 = -1e30f;
                            p[16 + reg] = s1;
                            mx = fmaxf(mx, s1);
                        }
                    }
                    mx = fmaxf(mx, __shfl_xor(mx, 32));
                    if (!__all(mx <= m + THR)) {          // defer-max (T13)
                        float mn = fmaxf(m, mx);
                        float a_ = exp2f(cexp * (m - mn));
                        m = mn;
                        #pragma unroll
                        for (int reg = 0; reg < 16; ++reg) {
                            int src = (reg & 3) + 8 * (reg >> 2) + 4 * hi;
                            float aq = __shfl(a_, src);
                            O0[reg] *= aq;
                            O1[reg] *= aq;
                        }
                        lr *= a_;
                    }
                    float cm = cexp * m;                  // exp2(cexp*p - cm)
                    float rs = 0.f;
                    #pragma unroll
                    for (int reg = 0; reg < 16; ++reg) {
                        p[reg] = exp2f(fmaf(cexp, p[reg], -cm));
                        rs += p[reg];
                    }
                    if (navail == 2) {
                        #pragma unroll
                        for (int reg = 16; reg < 32; ++reg) {
                            p[reg] = exp2f(fmaf(cexp, p[reg], -cm));
                            rs += p[reg];
                        }
                    }
                    rs += __shfl_xor(rs, 32);
                    lr += rs;

                    #pragma unroll
                    for (int c = 0; c < 4; ++c) {
                        if (c < navail * 2) {
                            int pb = (c >> 1) * 16 + (c & 1) * 8;
                            int pk01 = cvtpk(p[pb + 0], p[pb + 1]);
                            int pk23 = cvtpk(p[pb + 2], p[pb + 3]);
                            int pk45 = cvtpk(p[pb + 4], p[pb + 5]);
                            int pk67 = cvtpk(p[pb + 6], p[pb + 7]);
                            int sx01 = __shfl_xor(pk01, 32);
                            int sx23 = __shfl_xor(pk23, 32);
                            int sx45 = __shfl_xor(pk45, 32);
                            int sx67 = __shfl_xor(pk67, 32);
                            union { int i[4]; s16x8 v; } u;
                            u.i[0] = hi ? sx45 : pk01;
                            u.i[1] = hi ? sx67 : pk23;
                            u.i[2] = hi ? pk45 : sx01;
                            u.i[3] = hi ? pk67 : sx23;
                            int go = ((c * 2 + hi) ^ xg) * 8;
                            s16x8 vb0 = *(const s16x8*)&Vc[l32 * 64 + go];
                            O0 = mfma32(u.v, vb0, O0);
                            s16x8 vb1 = *(const s16x8*)&Vc[(32 + l32) * 64 + go];
                            O1 = mfma32(u.v, vb1, O1);
                        }
                    }
                }

                if (pre) {
                    #pragma unroll
                    for (int e = 0; e < 8; ++e) {
                        int d0 = w * 16 + e, d1 = w * 16 + 8 + e;
                        Vt[cur ^ 1][d0 * 64 + (l ^ ((d0 & 7) << 3))] = (u16)v0[e];
                        Vt[cur ^ 1][d1 * 64 + (l ^ ((d1 & 7) << 3))] = (u16)v1[e];
                    }
                }
                __syncthreads();
            }
        }

        size_t obase = (size_t)b * S * 1024 + h * 64;
        #pragma unroll
        for (int reg = 0; reg < 16; ++reg) {
            int src = (reg & 3) + 8 * (reg >> 2) + 4 * hi;
            size_t row = obase + (size_t)(qb + src) * 1024;
            pout[row + l32] = f2b(O0[reg]);
            pout[row + 32 + l32] = f2b(O1[reg]);
        }
        if (hi == 0) {
            float2 st; st.x = m; st.y = lr;
            stats[quar * 65536 + ((b * 2048 + qb + l32) * 16 + h)] = st;
        }
    }
}

// ------------------------- attention partial merge (x4) ---------------------
__global__ __launch_bounds__(256) void merge_attn(u16* __restrict__ p0,
                                                  const u16* __restrict__ p1,
                                                  const u16* __restrict__ p2,
                                                  const u16* __restrict__ p3,
                                                  const float2* __restrict__ stats) {
    constexpr float cexp = 0.18033688011112042f;
    int gid = blockIdx.x * 256 + threadIdx.x;    // [0, 65536*4)
    int rh = gid >> 2;
    int dc = (gid & 3) * 16;
    int R = rh >> 4, h = rh & 15;
    size_t addr = (size_t)R * 1024 + h * 64 + dc;

    float2 s0 = stats[rh];
    float2 s1 = stats[65536 + rh];
    float2 s2 = stats[131072 + rh];
    float2 s3 = stats[196608 + rh];
    float M = fmaxf(fmaxf(s0.x, s1.x), fmaxf(s2.x, s3.x));
    float a0 = exp2f(cexp * (s0.x - M));
    float a1 = exp2f(cexp * (s1.x - M));
    float a2 = exp2f(cexp * (s2.x - M));
    float a3 = exp2f(cexp * (s3.x - M));
    float inv = 1.f / (a0 * s0.y + a1 * s1.y + a2 * s2.y + a3 * s3.y);
    a0 *= inv; a1 *= inv; a2 *= inv; a3 *= inv;

    u16x4 o[4];
    #pragma unroll
    for (int j = 0; j < 4; ++j) {
        u16x4 q0 = *(const u16x4*)(p0 + addr + j * 4);
        u16x4 q1 = *(const u16x4*)(p1 + addr + j * 4);
        u16x4 q2 = *(const u16x4*)(p2 + addr + j * 4);
        u16x4 q3 = *(const u16x4*)(p3 + addr + j * 4);
        #pragma unroll
        for (int e = 0; e < 4; ++e)
            o[j][e] = f2b(a0 * b2f(q0[e]) + a1 * b2f(q1[e]) +
                          a2 * b2f(q2[e]) + a3 * b2f(q3[e]));
    }
    #pragma unroll
    for (int j = 0; j < 4; ++j)
        *(u16x4*)(p0 + addr + j * 4) = o[j];
}

// --------------------- residual + LayerNorm (row = 1024) --------------------
template<bool WB>
__global__ __launch_bounds__(256) void resln(const float* __restrict__ xa,
                                             const float* __restrict__ xb2,
                                             const float* __restrict__ g,
                                             const float* __restrict__ be,
                                             float* __restrict__ outf,
                                             u16* __restrict__ outb) {
    int row = blockIdx.x;
    int t = threadIdx.x;
    size_t base = (size_t)row * 1024 + t * 4;
    float4 va = *(const float4*)(xa + base);
    float4 vb = *(const float4*)(xb2 + base);
    float v0 = va.x + vb.x, v1 = va.y + vb.y, v2 = va.z + vb.z, v3 = va.w + vb.w;
    float s1 = v0 + v1 + v2 + v3;
    float s2 = v0 * v0 + v1 * v1 + v2 * v2 + v3 * v3;
    #pragma unroll
    for (int off = 32; off >= 1; off >>= 1) {
        s1 += __shfl_down(s1, off);
        s2 += __shfl_down(s2, off);
    }
    __shared__ float r1[4], r2[4];
    if ((t & 63) == 0) { r1[t >> 6] = s1; r2[t >> 6] = s2; }
    __syncthreads();
    s1 = r1[0] + r1[1] + r1[2] + r1[3];
    s2 = r2[0] + r2[1] + r2[2] + r2[3];
    float mean = s1 * (1.f / 1024.f);
    float var = fmaxf((s2 - 1024.f * mean * mean) * (1.f / 1023.f), 0.f);
    float inv = 1.f / (sqrtf(var) + 1e-6f);
    int col = t * 4;
    float y0 = g[col + 0] * ((v0 - mean) * inv) + be[col + 0];
    float y1 = g[col + 1] * ((v1 - mean) * inv) + be[col + 1];
    float y2 = g[col + 2] * ((v2 - mean) * inv) + be[col + 2];
    float y3 = g[col + 3] * ((v3 - mean) * inv) + be[col + 3];
    float4 o = {y0, y1, y2, y3};
    *(float4*)(outf + base) = o;
    if constexpr (WB) {
        u16x4 ob = {f2b(y0), f2b(y1), f2b(y2), f2b(y3)};
        *(u16x4*)(outb + base) = ob;
    }
}

// ---------------------------------------------------------------------------
extern "C" void kernel_launch(void* const* d_in, const int* in_sizes, int n_in,
                              void* d_out, int out_size, void* d_ws, size_t ws_size,
                              hipStream_t stream) {
    (void)in_sizes; (void)n_in; (void)out_size; (void)ws_size;
    const float* x       = (const float*)d_in[0];
    const float* w_attn  = (const float*)d_in[1];
    const float* b_attn  = (const float*)d_in[2];
    const float* w_aproj = (const float*)d_in[3];
    const float* b_aproj = (const float*)d_in[4];
    const float* g1      = (const float*)d_in[5];
    const float* b1      = (const float*)d_in[6];
    const float* w_fc    = (const float*)d_in[7];
    const float* b_fc    = (const float*)d_in[8];
    const float* w_mproj = (const float*)d_in[9];
    const float* b_mproj = (const float*)d_in[10];
    const float* g2      = (const float*)d_in[11];
    const float* b2      = (const float*)d_in[12];
    float* out = (float*)d_out;

    constexpr int M = 4096;           // B*S
    constexpr int D = 1024;

    char* ws = (char*)d_ws;
    u16*   slotA = (u16*)ws;                         // 32 MiB: qkv -> h
    char*  pB    = ws + (32u << 20);                 //  8 MiB: xb -> part0/abuf -> nb
    char*  pC    = ws + (40u << 20);                 //  8 MiB: part1 -> wT
    char*  pD    = ws + (48u << 20);                 // 16 MiB: part2+part3 -> aout -> mout
    char*  pE    = ws + (64u << 20);                 // 16 MiB: stats -> nbuf (fp32)

    u16*   xb    = (u16*)pB;
    u16*   wT    = (u16*)pC;
    u16*   qkv   = slotA;
    u16*   part0 = (u16*)pB;                         // becomes merged abuf
    u16*   part1 = (u16*)pC;
    u16*   part2 = (u16*)pD;
    u16*   part3 = (u16*)(pD + (8u << 20));
    float2* stat = (float2*)pE;
    u16*   abuf  = (u16*)pB;
    float* aout  = (float*)pD;
    float* nbuf  = (float*)pE;
    u16*   nb    = (u16*)pB;
    u16*   h     = slotA;
    float* mout  = (float*)pD;

    dim3 blk(256);

    cvt_bf16<<<dim3(4096), blk, 0, stream>>>(x, xb, M * D / 4);

    transpose_bf16<<<dim3(3072 / 32, 1024 / 32), blk, 0, stream>>>(w_attn, wT, 1024, 3072);
    gemm_pl<128, false, u16><<<dim3((M / 128) * (3072 / 128)), blk, 0, stream>>>(
        xb, wT, b_attn, qkv, M, 3072, 1024, 3072);

    attn_kernel<<<dim3(1024), blk, 0, stream>>>(qkv, part0, part1, part2, part3, stat);
    merge_attn<<<dim3(1024), blk, 0, stream>>>(part0, part1, part2, part3, stat);

    transpose_bf16<<<dim3(1024 / 32, 1024 / 32), blk, 0, stream>>>(w_aproj, wT, 1024, 1024);
    gemm_pl<64, false, float><<<dim3((M / 128) * (1024 / 64)), blk, 0, stream>>>(
        abuf, wT, b_aproj, aout, M, 1024, 1024, 1024);

    resln<true><<<dim3(M), blk, 0, stream>>>(x, aout, g1, b1, nbuf, nb);

    transpose_bf16<<<dim3(4096 / 32, 1024 / 32), blk, 0, stream>>>(w_fc, wT, 1024, 4096);
    gemm_pl<128, true, u16><<<dim3((M / 128) * (4096 / 128)), blk, 0, stream>>>(
        nb, wT, b_fc, h, M, 4096, 1024, 4096);

    transpose_bf16<<<dim3(1024 / 32, 4096 / 32), blk, 0, stream>>>(w_mproj, wT, 4096, 1024);
    gemm_pl<64, false, float><<<dim3((M / 128) * (1024 / 64)), blk, 0, stream>>>(
        h, wT, b_mproj, mout, M, 1024, 4096, 1024);

    resln<false><<<dim3(M), blk, 0, stream>>>(nbuf, mout, g2, b2, out, nullptr);
}

// Round 15
// 269.284 us; speedup vs baseline: 1.0632x; 1.0632x over previous
//
#include <hip/hip_runtime.h>
#include <type_traits>

// ---------------------------------------------------------------------------
// GPT block forward: B=2, S=2048, D=1024, H=16, DH=64
// Round 15: GEMM -> 512-thread blocks (8 waves, 2Mx4N) on the same 128xBN
// tile; LDS unchanged -> waves/CU doubles (16 @BN=128, 24 @BN=64).
// Sync schedule byte-identical to r13/r14 (counted vmcnt + raw barriers).
// Attention (kv-split x4)/merge/LN unchanged from round 12.
// ---------------------------------------------------------------------------

typedef unsigned short u16;
typedef short s16x8 __attribute__((ext_vector_type(8)));
typedef unsigned short u16x4 __attribute__((ext_vector_type(4)));
typedef float f32x4 __attribute__((ext_vector_type(4)));
typedef float f32x16 __attribute__((ext_vector_type(16)));

__device__ __forceinline__ u16 f2b(float f) {
    union { float f; unsigned u; } x{f};
    unsigned r = x.u + 0x7FFFu + ((x.u >> 16) & 1u);  // RNE
    return (u16)(r >> 16);
}

__device__ __forceinline__ float b2f(u16 v) {
    union { unsigned u; float f; } x;
    x.u = ((unsigned)v) << 16;
    return x.f;
}

__device__ __forceinline__ f32x4 mfma16(s16x8 a, s16x8 b, f32x4 c) {
    return __builtin_amdgcn_mfma_f32_16x16x32_bf16(a, b, c, 0, 0, 0);
}

__device__ __forceinline__ f32x16 mfma32(s16x8 a, s16x8 b, f32x16 c) {
    return __builtin_amdgcn_mfma_f32_32x32x16_bf16(a, b, c, 0, 0, 0);
}

__device__ __forceinline__ int cvtpk(float a, float b) {
    int r;
    asm("v_cvt_pk_bf16_f32 %0, %1, %2" : "=v"(r) : "v"(a), "v"(b));
    return r;
}

__device__ __forceinline__ void gld_lds16(const u16* g, const u16* l) {
    __builtin_amdgcn_global_load_lds(
        (const __attribute__((address_space(1))) void*)g,
        (__attribute__((address_space(3))) void*)l, 16, 0, 0);
}

__device__ __forceinline__ void hard_barrier() {
    __builtin_amdgcn_sched_barrier(0);
    __builtin_amdgcn_s_barrier();
    __builtin_amdgcn_sched_barrier(0);
}

// --------------------------- fp32 -> bf16 convert ---------------------------
__global__ __launch_bounds__(256) void cvt_bf16(const float* __restrict__ in,
                                                u16* __restrict__ out, int n4) {
    int i = blockIdx.x * 256 + threadIdx.x;
    if (i < n4) {
        float4 v = ((const float4*)in)[i];
        u16x4 o = {f2b(v.x), f2b(v.y), f2b(v.z), f2b(v.w)};
        ((u16x4*)out)[i] = o;
    }
}

// ------------------- transpose fp32 [K,N] -> bf16 [N,K] ---------------------
__global__ __launch_bounds__(256) void transpose_bf16(const float* __restrict__ W,
                                                      u16* __restrict__ WT,
                                                      int K, int N) {
    __shared__ float t[32][33];
    int tx = threadIdx.x & 31, ty = threadIdx.x >> 5;
    int n0 = blockIdx.x * 32, k0 = blockIdx.y * 32;
    #pragma unroll
    for (int r = ty; r < 32; r += 8)
        t[r][tx] = W[(size_t)(k0 + r) * N + n0 + tx];
    __syncthreads();
    #pragma unroll
    for (int r = ty; r < 32; r += 8)
        WT[(size_t)(n0 + r) * K + k0 + tx] = f2b(t[tx][r]);
}

// -------- MFMA GEMM, counted-vmcnt pipeline, 8 waves on 128xBN tile ---------
// 512 thr = 8 waves (2M x 4N); wave tile 64 x BN/4. BK=64 double-buffered;
// schedule = r13 verified (wait vmcnt(LTOT) keeps next tile in flight, raw
// barriers, stage k+2 after post-compute barrier). Full row&7 granule-XOR
// swizzle (0 bank conflicts, r10/r11). LDS 64/48 KiB -> 16/24 waves per CU.
template<int BN, bool GELU, typename OT>
__global__ __launch_bounds__(512) void gemm_pl(const u16* __restrict__ A,
                                               const u16* __restrict__ BT,
                                               const float* __restrict__ bias,
                                               OT* __restrict__ C,
                                               int M, int N, int K, int ldc) {
    constexpr int NF = BN / 64;           // n-frags per wave (1 or 2)
    constexpr int BNI = BN / 64;          // B staging instrs per thread
    constexpr int LTOT = 2 + BNI;         // loads per thread per K-tile
    __shared__ u16 As[2][128 * 64];
    __shared__ u16 Bs[2][BN * 64];

    int t = threadIdx.x;
    int w = t >> 6, l = t & 63, l16 = l & 15, lh = l >> 4;
    int wr = w >> 2, wc = w & 3;

    int nbm = M >> 7;
    int cpx = gridDim.x >> 3;
    int id = blockIdx.x;
    int id2 = (id & 7) * cpx + (id >> 3);
    size_t m0 = (size_t)(id2 % nbm) * 128;
    size_t n0 = (size_t)(id2 / nbm) * BN;

    // staging: instr j covers granules j*512+t; row = j*64 + (t>>3), source
    // col-granule pre-XORed with row&7 (row&7 == (t>>3)&7 since j*64%8==0).
    int rowA = t >> 3;                    // 0..63
    int gc2 = (t & 7) ^ (rowA & 7);
    const u16* Ag = A + (m0 + rowA) * (size_t)K + gc2 * 8;
    const u16* Bg = BT + (n0 + rowA) * (size_t)K + gc2 * 8;
    int wb = w * 512;                     // per-wave linear LDS base (u16)

    f32x4 acc[4][NF] = {};
    int rx = (l16 & 7) * 8;               // read-side granule XOR (u16 units)

    // prologue: tile 0 -> buf0, tile 1 -> buf1
    #pragma unroll
    for (int j = 0; j < 2; ++j)
        gld_lds16(Ag + (size_t)j * 64 * K, &As[0][j * 4096 + wb]);
    #pragma unroll
    for (int j = 0; j < BNI; ++j)
        gld_lds16(Bg + (size_t)j * 64 * K, &Bs[0][j * 4096 + wb]);
    #pragma unroll
    for (int j = 0; j < 2; ++j)
        gld_lds16(Ag + 64 + (size_t)j * 64 * K, &As[1][j * 4096 + wb]);
    #pragma unroll
    for (int j = 0; j < BNI; ++j)
        gld_lds16(Bg + 64 + (size_t)j * 64 * K, &Bs[1][j * 4096 + wb]);

#define GTILE(CB, kk, LAST)                                                   \
    {                                                                         \
        if (LAST) asm volatile("s_waitcnt vmcnt(0)" ::: "memory");            \
        else      asm volatile("s_waitcnt vmcnt(%0)" :: "n"(LTOT) : "memory");\
        hard_barrier();                                                       \
        __builtin_amdgcn_s_setprio(1);                                        \
        _Pragma("unroll")                                                     \
        for (int ks = 0; ks < 2; ++ks) {                                      \
            s16x8 af[4], bf[NF];                                              \
            _Pragma("unroll")                                                 \
            for (int fm = 0; fm < 4; ++fm) {                                  \
                int row = wr * 64 + fm * 16 + l16;                            \
                int col = ((ks * 4 + lh) * 8) ^ rx;                           \
                af[fm] = *(const s16x8*)&As[CB][row * 64 + col];              \
            }                                                                 \
            _Pragma("unroll")                                                 \
            for (int fn = 0; fn < NF; ++fn) {                                 \
                int row = wc * (BN / 4) + fn * 16 + l16;                      \
                int col = ((ks * 4 + lh) * 8) ^ rx;                           \
                bf[fn] = *(const s16x8*)&Bs[CB][row * 64 + col];              \
            }                                                                 \
            _Pragma("unroll")                                                 \
            for (int fm = 0; fm < 4; ++fm)                                    \
                _Pragma("unroll")                                             \
                for (int fn = 0; fn < NF; ++fn)                               \
                    acc[fm][fn] = mfma16(af[fm], bf[fn], acc[fm][fn]);        \
        }                                                                     \
        __builtin_amdgcn_s_setprio(0);                                        \
        hard_barrier();                                                       \
        if ((kk) + 128 < K) {                                                 \
            const u16* Ap = Ag + (kk) + 128;                                  \
            _Pragma("unroll")                                                 \
            for (int j = 0; j < 2; ++j)                                       \
                gld_lds16(Ap + (size_t)j * 64 * K, &As[CB][j * 4096 + wb]);   \
            const u16* Bp = Bg + (kk) + 128;                                  \
            _Pragma("unroll")                                                 \
            for (int j = 0; j < BNI; ++j)                                     \
                gld_lds16(Bp + (size_t)j * 64 * K, &Bs[CB][j * 4096 + wb]);   \
        }                                                                     \
    }

    // K is a multiple of 128 here (1024 or 4096)
    for (int k0 = 0; k0 < K; k0 += 128) {
        GTILE(0, k0, (k0 + 64 >= K))
        GTILE(1, k0 + 64, (k0 + 128 >= K))
    }
#undef GTILE

    #pragma unroll
    for (int fn = 0; fn < NF; ++fn) {
        size_t col = n0 + wc * (BN / 4) + fn * 16 + l16;
        float bs = bias[col];
        #pragma unroll
        for (int fm = 0; fm < 4; ++fm) {
            size_t row0 = m0 + wr * 64 + fm * 16 + lh * 4;
            #pragma unroll
            for (int i = 0; i < 4; ++i) {
                float v = acc[fm][fn][i] + bs;
                if constexpr (GELU) {
                    float x3 = v * v * v;
                    v = 0.5f * v * (1.f + tanhf(0.7978845608f * (v + 0.044715f * x3)));
                }
                if constexpr (std::is_same<OT, u16>::value)
                    C[(row0 + i) * ldc + col] = f2b(v);
                else
                    C[(row0 + i) * ldc + col] = v;
            }
        }
    }
}

// --------------------------- causal attention -------------------------------
// kv-split x4 (round 12, verified): block = (quarter, pair pr, bh).
__global__ __launch_bounds__(256) void attn_kernel(const u16* __restrict__ qkv,
                                                   u16* __restrict__ p0,
                                                   u16* __restrict__ p1,
                                                   u16* __restrict__ p2,
                                                   u16* __restrict__ p3,
                                                   float2* __restrict__ stats) {
    constexpr int S = 2048, D3 = 3072, Dm = 1024;
    __shared__ u16 Kl[2][64 * 64];
    __shared__ u16 Vt[2][64 * 64];

    int t = threadIdx.x;
    int w = t >> 6, l = t & 63;
    int l32 = l & 31, hi = l >> 5;
    int bid = blockIdx.x;
    int bh = bid & 31;
    int pr = (bid >> 5) & 7;
    int quar = bid >> 8;                // 0..3
    int b = bh >> 4, h = bh & 15;
    size_t base = (size_t)b * S * D3;

    u16* pout = quar == 0 ? p0 : (quar == 1 ? p1 : (quar == 2 ? p2 : p3));

    int rK0 = t >> 3, gK = t & 7;
    int rK1 = rK0 + 32;
    size_t koff0 = (size_t)rK0 * D3 + (size_t)((gK ^ (rK0 & 7)) * 8);
    size_t koff1 = (size_t)rK1 * D3 + (size_t)((gK ^ (rK1 & 7)) * 8);
    const u16* kbase = qkv + base + Dm + h * 64;
    const u16* vbase = qkv + base + 2 * Dm + h * 64 + w * 16;

    constexpr float cexp = 0.18033688011112042f;   // 0.125 * log2(e)
    constexpr float THR = 64.0f;                    // defer-max threshold
    int xg = l32 & 7;

    #pragma unroll 1
    for (int ph = 0; ph < 2; ++ph) {
        int qt = ph ? (15 - pr) : pr;
        int qb = qt * 128 + w * 32;
        int nst = 2 * (qt + 1);
        int c0 = (nst * quar) >> 2;
        int c1 = (nst * (quar + 1)) >> 2;

        f32x16 O0 = {}, O1 = {};
        float m = -1e30f, lr = 0.f;

        if (c0 < c1) {
            s16x8 qf[4];
            const u16* qp = qkv + base + (size_t)(qb + l32) * D3 + h * 64 + hi * 8;
            #pragma unroll
            for (int kk = 0; kk < 4; ++kk)
                qf[kk] = *(const s16x8*)(qp + kk * 16);

            size_t kc0 = (size_t)c0 * 64 * D3;
            gld_lds16(kbase + kc0 + koff0, &Kl[0][w * 512]);
            gld_lds16(kbase + kc0 + koff1, &Kl[0][2048 + w * 512]);
            {
                const u16* vp = vbase + (size_t)(c0 * 64 + l) * D3;
                s16x8 pv0 = *(const s16x8*)vp;
                s16x8 pv1 = *(const s16x8*)(vp + 8);
                #pragma unroll
                for (int e = 0; e < 8; ++e) {
                    int d0 = w * 16 + e, d1 = w * 16 + 8 + e;
                    Vt[0][d0 * 64 + (l ^ ((d0 & 7) << 3))] = (u16)pv0[e];
                    Vt[0][d1 * 64 + (l ^ ((d1 & 7) << 3))] = (u16)pv1[e];
                }
            }
            __syncthreads();

            #pragma unroll 1
            for (int sc = c0; sc < c1; ++sc) {
                int cur = (sc - c0) & 1;
                bool pre = (sc + 1 < c1);
                s16x8 v0, v1;
                if (pre) {
                    size_t koffc = (size_t)(sc + 1) * 64 * D3;
                    gld_lds16(kbase + koffc + koff0, &Kl[cur ^ 1][w * 512]);
                    gld_lds16(kbase + koffc + koff1, &Kl[cur ^ 1][2048 + w * 512]);
                    const u16* vp = vbase + (size_t)((sc + 1) * 64 + l) * D3;
                    v0 = *(const s16x8*)vp;
                    v1 = *(const s16x8*)(vp + 8);
                }

                int kvb = sc * 64;
                int navail = ((qb - kvb) >> 5) + 1;
                if (navail > 0) {
                    if (navail > 2) navail = 2;
                    const u16* Kc = Kl[cur];
                    const u16* Vc = Vt[cur];
                    f32x16 sa0 = {}, sa1 = {};
                    #pragma unroll
                    for (int kk = 0; kk < 4; ++kk) {
                        s16x8 kf = *(const s16x8*)&Kc[l32 * 64 + (((2 * kk + hi) ^ xg) * 8)];
                        sa0 = mfma32(kf, qf[kk], sa0);
                    }
                    if (navail == 2) {
                        #pragma unroll
                        for (int kk = 0; kk < 4; ++kk) {
                            s16x8 kf = *(const s16x8*)&Kc[(32 + l32) * 64 + (((2 * kk + hi) ^ xg) * 8)];
                            sa1 = mfma32(kf, qf[kk], sa1);
                        }
                    }
                    bool diag0 = (kvb == qb);
                    bool diag1 = (kvb + 32 == qb);
                    float p[32];
                    float mx = -1e30f;
                    #pragma unroll
                    for (int reg = 0; reg < 16; ++reg) {
                        int kvloc = (reg & 3) + 8 * (reg >> 2) + 4 * hi;
                        float s0 = sa0[reg];
                        if (diag0 && kvloc > l32) s0 = -1e30f;
                        p[reg] = s0;
                        mx = fmaxf(mx, s0);
                    }
                    if (navail == 2) {
                        #pragma unroll
                        for (int reg = 0; reg < 16; ++reg) {
                            int kvloc = (reg & 3) + 8 * (reg >> 2) + 4 * hi;
                            float s1 = sa1[reg];
                            if (diag1 && kvloc > l32) s1 = -1e30f;
                            p[16 + reg] = s1;
                            mx = fmaxf(mx, s1);
                        }
                    }
                    mx = fmaxf(mx, __shfl_xor(mx, 32));
                    if (!__all(mx <= m + THR)) {          // defer-max (T13)
                        float mn = fmaxf(m, mx);
                        float a_ = exp2f(cexp * (m - mn));
                        m = mn;
                        #pragma unroll
                        for (int reg = 0; reg < 16; ++reg) {
                            int src = (reg & 3) + 8 * (reg >> 2) + 4 * hi;
                            float aq = __shfl(a_, src);
                            O0[reg] *= aq;
                            O1[reg] *= aq;
                        }
                        lr *= a_;
                    }
                    float cm = cexp * m;                  // exp2(cexp*p - cm)
                    float rs = 0.f;
                    #pragma unroll
                    for (int reg = 0; reg < 16; ++reg) {
                        p[reg] = exp2f(fmaf(cexp, p[reg], -cm));
                        rs += p[reg];
                    }
                    if (navail == 2) {
                        #pragma unroll
                        for (int reg = 16; reg < 32; ++reg) {
                            p[reg] = exp2f(fmaf(cexp, p[reg], -cm));
                            rs += p[reg];
                        }
                    }
                    rs += __shfl_xor(rs, 32);
                    lr += rs;

                    #pragma unroll
                    for (int c = 0; c < 4; ++c) {
                        if (c < navail * 2) {
                            int pb = (c >> 1) * 16 + (c & 1) * 8;
                            int pk01 = cvtpk(p[pb + 0], p[pb + 1]);
                            int pk23 = cvtpk(p[pb + 2], p[pb + 3]);
                            int pk45 = cvtpk(p[pb + 4], p[pb + 5]);
                            int pk67 = cvtpk(p[pb + 6], p[pb + 7]);
                            int sx01 = __shfl_xor(pk01, 32);
                            int sx23 = __shfl_xor(pk23, 32);
                            int sx45 = __shfl_xor(pk45, 32);
                            int sx67 = __shfl_xor(pk67, 32);
                            union { int i[4]; s16x8 v; } u;
                            u.i[0] = hi ? sx45 : pk01;
                            u.i[1] = hi ? sx67 : pk23;
                            u.i[2] = hi ? pk45 : sx01;
                            u.i[3] = hi ? pk67 : sx23;
                            int go = ((c * 2 + hi) ^ xg) * 8;
                            s16x8 vb0 = *(const s16x8*)&Vc[l32 * 64 + go];
                            O0 = mfma32(u.v, vb0, O0);
                            s16x8 vb1 = *(const s16x8*)&Vc[(32 + l32) * 64 + go];
                            O1 = mfma32(u.v, vb1, O1);
                        }
                    }
                }

                if (pre) {
                    #pragma unroll
                    for (int e = 0; e < 8; ++e) {
                        int d0 = w * 16 + e, d1 = w * 16 + 8 + e;
                        Vt[cur ^ 1][d0 * 64 + (l ^ ((d0 & 7) << 3))] = (u16)v0[e];
                        Vt[cur ^ 1][d1 * 64 + (l ^ ((d1 & 7) << 3))] = (u16)v1[e];
                    }
                }
                __syncthreads();
            }
        }

        size_t obase = (size_t)b * S * 1024 + h * 64;
        #pragma unroll
        for (int reg = 0; reg < 16; ++reg) {
            int src = (reg & 3) + 8 * (reg >> 2) + 4 * hi;
            size_t row = obase + (size_t)(qb + src) * 1024;
            pout[row + l32] = f2b(O0[reg]);
            pout[row + 32 + l32] = f2b(O1[reg]);
        }
        if (hi == 0) {
            float2 st; st.x = m; st.y = lr;
            stats[quar * 65536 + ((b * 2048 + qb + l32) * 16 + h)] = st;
        }
    }
}

// ------------------------- attention partial merge (x4) ---------------------
__global__ __launch_bounds__(256) void merge_attn(u16* __restrict__ p0,
                                                  const u16* __restrict__ p1,
                                                  const u16* __restrict__ p2,
                                                  const u16* __restrict__ p3,
                                                  const float2* __restrict__ stats) {
    constexpr float cexp = 0.18033688011112042f;
    int gid = blockIdx.x * 256 + threadIdx.x;    // [0, 65536*4)
    int rh = gid >> 2;
    int dc = (gid & 3) * 16;
    int R = rh >> 4, h = rh & 15;
    size_t addr = (size_t)R * 1024 + h * 64 + dc;

    float2 s0 = stats[rh];
    float2 s1 = stats[65536 + rh];
    float2 s2 = stats[131072 + rh];
    float2 s3 = stats[196608 + rh];
    float M = fmaxf(fmaxf(s0.x, s1.x), fmaxf(s2.x, s3.x));
    float a0 = exp2f(cexp * (s0.x - M));
    float a1 = exp2f(cexp * (s1.x - M));
    float a2 = exp2f(cexp * (s2.x - M));
    float a3 = exp2f(cexp * (s3.x - M));
    float inv = 1.f / (a0 * s0.y + a1 * s1.y + a2 * s2.y + a3 * s3.y);
    a0 *= inv; a1 *= inv; a2 *= inv; a3 *= inv;

    u16x4 o[4];
    #pragma unroll
    for (int j = 0; j < 4; ++j) {
        u16x4 q0 = *(const u16x4*)(p0 + addr + j * 4);
        u16x4 q1 = *(const u16x4*)(p1 + addr + j * 4);
        u16x4 q2 = *(const u16x4*)(p2 + addr + j * 4);
        u16x4 q3 = *(const u16x4*)(p3 + addr + j * 4);
        #pragma unroll
        for (int e = 0; e < 4; ++e)
            o[j][e] = f2b(a0 * b2f(q0[e]) + a1 * b2f(q1[e]) +
                          a2 * b2f(q2[e]) + a3 * b2f(q3[e]));
    }
    #pragma unroll
    for (int j = 0; j < 4; ++j)
        *(u16x4*)(p0 + addr + j * 4) = o[j];
}

// --------------------- residual + LayerNorm (row = 1024) --------------------
template<bool WB>
__global__ __launch_bounds__(256) void resln(const float* __restrict__ xa,
                                             const float* __restrict__ xb2,
                                             const float* __restrict__ g,
                                             const float* __restrict__ be,
                                             float* __restrict__ outf,
                                             u16* __restrict__ outb) {
    int row = blockIdx.x;
    int t = threadIdx.x;
    size_t base = (size_t)row * 1024 + t * 4;
    float4 va = *(const float4*)(xa + base);
    float4 vb = *(const float4*)(xb2 + base);
    float v0 = va.x + vb.x, v1 = va.y + vb.y, v2 = va.z + vb.z, v3 = va.w + vb.w;
    float s1 = v0 + v1 + v2 + v3;
    float s2 = v0 * v0 + v1 * v1 + v2 * v2 + v3 * v3;
    #pragma unroll
    for (int off = 32; off >= 1; off >>= 1) {
        s1 += __shfl_down(s1, off);
        s2 += __shfl_down(s2, off);
    }
    __shared__ float r1[4], r2[4];
    if ((t & 63) == 0) { r1[t >> 6] = s1; r2[t >> 6] = s2; }
    __syncthreads();
    s1 = r1[0] + r1[1] + r1[2] + r1[3];
    s2 = r2[0] + r2[1] + r2[2] + r2[3];
    float mean = s1 * (1.f / 1024.f);
    float var = fmaxf((s2 - 1024.f * mean * mean) * (1.f / 1023.f), 0.f);
    float inv = 1.f / (sqrtf(var) + 1e-6f);
    int col = t * 4;
    float y0 = g[col + 0] * ((v0 - mean) * inv) + be[col + 0];
    float y1 = g[col + 1] * ((v1 - mean) * inv) + be[col + 1];
    float y2 = g[col + 2] * ((v2 - mean) * inv) + be[col + 2];
    float y3 = g[col + 3] * ((v3 - mean) * inv) + be[col + 3];
    float4 o = {y0, y1, y2, y3};
    *(float4*)(outf + base) = o;
    if constexpr (WB) {
        u16x4 ob = {f2b(y0), f2b(y1), f2b(y2), f2b(y3)};
        *(u16x4*)(outb + base) = ob;
    }
}

// ---------------------------------------------------------------------------
extern "C" void kernel_launch(void* const* d_in, const int* in_sizes, int n_in,
                              void* d_out, int out_size, void* d_ws, size_t ws_size,
                              hipStream_t stream) {
    (void)in_sizes; (void)n_in; (void)out_size; (void)ws_size;
    const float* x       = (const float*)d_in[0];
    const float* w_attn  = (const float*)d_in[1];
    const float* b_attn  = (const float*)d_in[2];
    const float* w_aproj = (const float*)d_in[3];
    const float* b_aproj = (const float*)d_in[4];
    const float* g1      = (const float*)d_in[5];
    const float* b1      = (const float*)d_in[6];
    const float* w_fc    = (const float*)d_in[7];
    const float* b_fc    = (const float*)d_in[8];
    const float* w_mproj = (const float*)d_in[9];
    const float* b_mproj = (const float*)d_in[10];
    const float* g2      = (const float*)d_in[11];
    const float* b2      = (const float*)d_in[12];
    float* out = (float*)d_out;

    constexpr int M = 4096;           // B*S
    constexpr int D = 1024;

    char* ws = (char*)d_ws;
    u16*   slotA = (u16*)ws;                         // 32 MiB: qkv -> h
    char*  pB    = ws + (32u << 20);                 //  8 MiB: xb -> part0/abuf -> nb
    char*  pC    = ws + (40u << 20);                 //  8 MiB: part1 -> wT
    char*  pD    = ws + (48u << 20);                 // 16 MiB: part2+part3 -> aout -> mout
    char*  pE    = ws + (64u << 20);                 // 16 MiB: stats -> nbuf (fp32)

    u16*   xb    = (u16*)pB;
    u16*   wT    = (u16*)pC;
    u16*   qkv   = slotA;
    u16*   part0 = (u16*)pB;                         // becomes merged abuf
    u16*   part1 = (u16*)pC;
    u16*   part2 = (u16*)pD;
    u16*   part3 = (u16*)(pD + (8u << 20));
    float2* stat = (float2*)pE;
    u16*   abuf  = (u16*)pB;
    float* aout  = (float*)pD;
    float* nbuf  = (float*)pE;
    u16*   nb    = (u16*)pB;
    u16*   h     = slotA;
    float* mout  = (float*)pD;

    dim3 blk(256);
    dim3 blk512(512);

    cvt_bf16<<<dim3(4096), blk, 0, stream>>>(x, xb, M * D / 4);

    transpose_bf16<<<dim3(3072 / 32, 1024 / 32), blk, 0, stream>>>(w_attn, wT, 1024, 3072);
    gemm_pl<128, false, u16><<<dim3((M / 128) * (3072 / 128)), blk512, 0, stream>>>(
        xb, wT, b_attn, qkv, M, 3072, 1024, 3072);

    attn_kernel<<<dim3(1024), blk, 0, stream>>>(qkv, part0, part1, part2, part3, stat);
    merge_attn<<<dim3(1024), blk, 0, stream>>>(part0, part1, part2, part3, stat);

    transpose_bf16<<<dim3(1024 / 32, 1024 / 32), blk, 0, stream>>>(w_aproj, wT, 1024, 1024);
    gemm_pl<64, false, float><<<dim3((M / 128) * (1024 / 64)), blk512, 0, stream>>>(
        abuf, wT, b_aproj, aout, M, 1024, 1024, 1024);

    resln<true><<<dim3(M), blk, 0, stream>>>(x, aout, g1, b1, nbuf, nb);

    transpose_bf16<<<dim3(4096 / 32, 1024 / 32), blk, 0, stream>>>(w_fc, wT, 1024, 4096);
    gemm_pl<128, true, u16><<<dim3((M / 128) * (4096 / 128)), blk512, 0, stream>>>(
        nb, wT, b_fc, h, M, 4096, 1024, 4096);

    transpose_bf16<<<dim3(1024 / 32, 4096 / 32), blk, 0, stream>>>(w_mproj, wT, 4096, 1024);
    gemm_pl<64, false, float><<<dim3((M / 128) * (1024 / 64)), blk512, 0, stream>>>(
        h, wT, b_mproj, mout, M, 1024, 4096, 1024);

    resln<false><<<dim3(M), blk, 0, stream>>>(nbuf, mout, g2, b2, out, nullptr);
}